// Round 3
// baseline (976.222 us; speedup 1.0000x reference)
//
#include <hip/hip_runtime.h>
#include <stdint.h>

#define L_SEQ 2048
#define B_SZ 2
#define NHH 8
#define HDD 128
#define C_SZ 1024
#define EMB_D 33
#define ORD 64
#define BANDS 16
#define FSTRIDE (L_SEQ + 256)   // 256 leading zeros per filter row for causal masking

// ---------------------------------------------------------------------------
// Kernel 1: hyena filter MLP -> filt[hd][FSTRIDE] f32 (row = 256 zeros | 2048 taps)
// Block = 256 threads = 4 l-values x 64 "order" lanes. grid = 512.
// filt[hd][lag 0] += D[hd]  (absorbs the kv*D term).
// ---------------------------------------------------------------------------
__global__ void filter_kernel(const float* __restrict__ w0, const float* __restrict__ b0,
                              const float* __restrict__ w1, const float* __restrict__ b1,
                              const float* __restrict__ w2, const float* __restrict__ b2,
                              const float* __restrict__ fr, const float* __restrict__ wf,
                              const float* __restrict__ md, const float* __restrict__ Dv,
                              float* __restrict__ filt) {
  int tid = threadIdx.x;
  int o = tid & 63;
  int lq = tid >> 6;                 // 0..3
  int l = blockIdx.x * 4 + lq;

  // zero the 256-elem pad before each of the 128 filter rows (first 128 blocks)
  if (blockIdx.x < 128) filt[(size_t)blockIdx.x * FSTRIDE + tid] = 0.0f;

  __shared__ float zs[4][EMB_D];
  __shared__ float hs[4][ORD];
  __shared__ float gs[4][ORD];

  float t = (float)l / (float)(L_SEQ - 1);
  float wang = 6.2831853071795864f * (float)l / (float)L_SEQ;
  const float fstep = (15.0f - 1e-4f) / 15.0f;

  if (o == 0) zs[lq][0] = t;
  if (o >= 1 && o < 1 + BANDS) {
    int j = o - 1;
    float fj = 1e-4f + fstep * (float)j;
    zs[lq][1 + j] = cosf(wang * fj);
  }
  if (o >= 1 + BANDS && o < 1 + 2 * BANDS) {
    int j = o - 1 - BANDS;
    float fj = 1e-4f + fstep * (float)j;
    zs[lq][1 + BANDS + j] = -sinf(wang * fj);
  }
  __syncthreads();

  float fo = fr[o];
  float a = b0[o];
  for (int e = 0; e < EMB_D; ++e) a += zs[lq][e] * w0[o * EMB_D + e];
  hs[lq][o] = sinf(fo * a);
  __syncthreads();

  a = b1[o];
  for (int e = 0; e < ORD; ++e) a += hs[lq][e] * w1[o * ORD + e];
  gs[lq][o] = sinf(fo * a);
  __syncthreads();

  a = b2[o];
  for (int e = 0; e < ORD; ++e) a += gs[lq][e] * w2[o * ORD + e];
  float h3 = sinf(fo * a);
  __syncthreads();
  hs[lq][o] = h3;
  __syncthreads();

  #pragma unroll
  for (int pass = 0; pass < 2; ++pass) {
    int hd = pass * 64 + o;
    float acc = 0.0f;
    for (int e = 0; e < ORD; ++e) acc += hs[lq][e] * wf[hd * ORD + e];
    float val = acc * expf(-t * fabsf(md[hd]));
    if (l == 0) val += Dv[hd];   // absorb D term into lag-0 tap
    filt[(size_t)hd * FSTRIDE + 256 + l] = val;
  }
}

// ---------------------------------------------------------------------------
// Kernel 2: depthwise causal 3-tap conv + layout transform.
// in : [L,B,NH,HD] f32  (c_orig = np*128 + hn)
// out: A[b][hd_fft][l][n1] f32, where c_orig = hd_fft*8 + n1 (the fftconv split)
// Block handles (b, np, 64-l tile) for all 128 hn; loops q/k/v.
// ---------------------------------------------------------------------------
#define TLC 64
__global__ void shortconv_kernel(const float* __restrict__ q_in,
                                 const float* __restrict__ k_in,
                                 const float* __restrict__ v_in,
                                 const float* __restrict__ scw,
                                 const float* __restrict__ scb,
                                 float* __restrict__ Aq, float* __restrict__ Ak,
                                 float* __restrict__ Av) {
  int bid = blockIdx.x;
  int lt = bid & 31;
  int np = (bid >> 5) & 7;
  int b = bid >> 8;
  int l0 = lt * TLC;
  int tid = threadIdx.x;

  __shared__ float xs[TLC + 2][HDD + 4];      // +4 pad: breaks 512B-stride bank aliasing
  __shared__ float wcs[HDD][4];               // w0,w1,w2,bias per hn

  const float* ins[3] = {q_in, k_in, v_in};
  float* outs[3] = {Aq, Ak, Av};

  for (int tsr = 0; tsr < 3; ++tsr) {
    const float* x = ins[tsr];
    if (tid < HDD) {
      int c = np * HDD + tid;
      wcs[tid][0] = scw[(tsr * C_SZ + c) * 3 + 0];
      wcs[tid][1] = scw[(tsr * C_SZ + c) * 3 + 1];
      wcs[tid][2] = scw[(tsr * C_SZ + c) * 3 + 2];
      wcs[tid][3] = scb[tsr * C_SZ + c];
    }
    for (int idx = tid; idx < (TLC + 2) * HDD; idx += 256) {
      int row = idx >> 7, hn = idx & 127;
      int l = l0 - 2 + row;                  // row 0 <-> l0-2
      float val = 0.0f;
      if (l >= 0) val = x[(((size_t)l * B_SZ + b) * NHH + np) * HDD + hn];
      xs[row][hn] = val;
    }
    __syncthreads();

    int n1 = tid & 7;
    int lp = tid >> 3;                        // 0..31
    float* outp = outs[tsr];
    for (int hdi = 0; hdi < 16; ++hdi) {
      int hn = hdi * 8 + n1;
      float cw0 = wcs[hn][0], cw1 = wcs[hn][1], cw2 = wcs[hn][2], cb = wcs[hn][3];
      int hd = np * 16 + hdi;
      #pragma unroll
      for (int half = 0; half < 2; ++half) {
        int ll = half * 32 + lp;
        // y[l] = b + w0*x[l-2] + w1*x[l-1] + w2*x[l]
        float y = cb + cw0 * xs[ll][hn] + cw1 * xs[ll + 1][hn]
                     + cw2 * xs[ll + 2][hn];
        outp[(((size_t)b * HDD + hd) * L_SEQ + (l0 + ll)) * NHH + n1] = y;
      }
    }
    __syncthreads();
  }
}

// ---------------------------------------------------------------------------
// Kernel 3: main causal outer-product conv.
// out[b,n2,hd,l] = sum_{m<=l} filt+[hd][l-m] * (sum_n1 Aq[l,n1]*Av[m,n1]) * Ak[m,n2]
// Block = (b, hd, half). 4 waves x 256 contiguous rows; lane owns 4 rows x 8 n2.
// Causality: filter rows are zero-padded 256 in front, so negative lags read 0.
// ---------------------------------------------------------------------------
__global__ void __launch_bounds__(256, 2)
hyena_main(const float* __restrict__ Aq, const float* __restrict__ Ak,
           const float* __restrict__ Av, const float* __restrict__ filt,
           float* __restrict__ out) {
  int bid = blockIdx.x;                 // 512 = B * HD * 2
  int seg = bid & 1;
  int hd = (bid >> 1) & 127;
  int b = bid >> 8;
  int wave = threadIdx.x >> 6;
  int lane = threadIdx.x & 63;
  int wb = seg * 1024 + wave * 256;     // wave's contiguous 256-row range

  const float* fp = filt + (size_t)hd * FSTRIDE + 256;
  size_t base = ((size_t)b * HDD + hd) * L_SEQ * NHH;
  const float* aqb = Aq + base;
  const float* avb = Av + base;
  const float* akb = Ak + base;

  float qv[4][8], acc[4][8];
  #pragma unroll
  for (int r = 0; r < 4; ++r) {
    int l = wb + lane + 64 * r;
    const float4* qp = (const float4*)(aqb + (size_t)l * 8);
    float4 q0 = qp[0], q1 = qp[1];
    qv[r][0] = q0.x; qv[r][1] = q0.y; qv[r][2] = q0.z; qv[r][3] = q0.w;
    qv[r][4] = q1.x; qv[r][5] = q1.y; qv[r][6] = q1.z; qv[r][7] = q1.w;
    #pragma unroll
    for (int j = 0; j < 8; ++j) acc[r][j] = 0.0f;
  }

  int m_end = wb + 256;                 // rows in [wb, wb+256): need m <= l < m_end
  for (int m = 0; m < m_end; ++m) {
    const float4* ap = (const float4*)(avb + (size_t)m * 8);
    float4 a0 = ap[0], a1 = ap[1];      // Av row m (wave-uniform)
    const float4* kp = (const float4*)(akb + (size_t)m * 8);
    float4 k0 = kp[0], k1 = kp[1];      // Ak row m (wave-uniform)
    #pragma unroll
    for (int r = 0; r < 4; ++r) {
      int l = wb + lane + 64 * r;
      float S = qv[r][0]*a0.x + qv[r][1]*a0.y + qv[r][2]*a0.z + qv[r][3]*a0.w
              + qv[r][4]*a1.x + qv[r][5]*a1.y + qv[r][6]*a1.z + qv[r][7]*a1.w;
      float wgt = fp[l - m];            // 0.0 from pad when m > l
      float tt = wgt * S;
      acc[r][0] += tt*k0.x; acc[r][1] += tt*k0.y; acc[r][2] += tt*k0.z; acc[r][3] += tt*k0.w;
      acc[r][4] += tt*k1.x; acc[r][5] += tt*k1.y; acc[r][6] += tt*k1.z; acc[r][7] += tt*k1.w;
    }
  }

  // out[b, np, l, hn]: np = hd>>4, hn = (hd&15)*8 + n2 -> 8 contiguous f32 per row
  int np = hd >> 4;
  int hnb = (hd & 15) * 8;
  #pragma unroll
  for (int r = 0; r < 4; ++r) {
    int l = wb + lane + 64 * r;
    size_t oidx = (((size_t)b * NHH + np) * L_SEQ + l) * HDD + hnb;
    float4* op = (float4*)(out + oidx);
    op[0] = make_float4(acc[r][0], acc[r][1], acc[r][2], acc[r][3]);
    op[1] = make_float4(acc[r][4], acc[r][5], acc[r][6], acc[r][7]);
  }
}

// ---------------------------------------------------------------------------
extern "C" void kernel_launch(void* const* d_in, const int* in_sizes, int n_in,
                              void* d_out, int out_size, void* d_ws, size_t ws_size,
                              hipStream_t stream) {
  const float* q_in = (const float*)d_in[0];
  const float* k_in = (const float*)d_in[1];
  const float* v_in = (const float*)d_in[2];
  const float* scw  = (const float*)d_in[3];
  const float* scb  = (const float*)d_in[4];
  const float* Dv   = (const float*)d_in[5];
  const float* w0   = (const float*)d_in[6];
  const float* b0   = (const float*)d_in[7];
  const float* w1   = (const float*)d_in[8];
  const float* b1   = (const float*)d_in[9];
  const float* w2   = (const float*)d_in[10];
  const float* b2   = (const float*)d_in[11];
  const float* fr   = (const float*)d_in[12];
  const float* wf   = (const float*)d_in[13];
  const float* md   = (const float*)d_in[14];

  float* ws   = (float*)d_ws;
  float* filt = ws;                                        // 128*2304 f32
  float* Aq   = ws + (size_t)HDD * FSTRIDE;                // each 2*128*2048*8 f32
  float* Ak   = Aq + (size_t)B_SZ * HDD * L_SEQ * NHH;
  float* Av   = Ak + (size_t)B_SZ * HDD * L_SEQ * NHH;

  filter_kernel<<<512, 256, 0, stream>>>(w0, b0, w1, b1, w2, b2, fr, wf, md, Dv, filt);
  shortconv_kernel<<<512, 256, 0, stream>>>(q_in, k_in, v_in, scw, scb, Aq, Ak, Av);
  hyena_main<<<512, 256, 0, stream>>>(Aq, Ak, Av, filt, (float*)d_out);
}

// Round 4
// 643.576 us; speedup vs baseline: 1.5169x; 1.5169x over previous
//
#include <hip/hip_runtime.h>
#include <stdint.h>

#define L_SEQ 2048
#define B_SZ 2
#define NHH 8
#define HDD 128
#define C_SZ 1024
#define EMB_D 33
#define ORD 64
#define BANDS 16
#define FSTRIDE (L_SEQ + 256)   // 256 leading zeros per filter row for causal masking

// ---------------------------------------------------------------------------
// Kernel 1: hyena filter MLP -> filt[hd][FSTRIDE] f32 (row = 256 zeros | 2048 taps)
// Block = 256 threads = 4 l-values x 64 "order" lanes. grid = 512.
// filt[hd][lag 0] += D[hd]  (absorbs the kv*D term).
// ---------------------------------------------------------------------------
__global__ void filter_kernel(const float* __restrict__ w0, const float* __restrict__ b0,
                              const float* __restrict__ w1, const float* __restrict__ b1,
                              const float* __restrict__ w2, const float* __restrict__ b2,
                              const float* __restrict__ fr, const float* __restrict__ wf,
                              const float* __restrict__ md, const float* __restrict__ Dv,
                              float* __restrict__ filt) {
  int tid = threadIdx.x;
  int o = tid & 63;
  int lq = tid >> 6;                 // 0..3
  int l = blockIdx.x * 4 + lq;

  // zero the 256-elem pad before each of the 128 filter rows (first 128 blocks)
  if (blockIdx.x < 128) filt[(size_t)blockIdx.x * FSTRIDE + tid] = 0.0f;

  __shared__ float zs[4][EMB_D];
  __shared__ float hs[4][ORD];
  __shared__ float gs[4][ORD];

  float t = (float)l / (float)(L_SEQ - 1);
  float wang = 6.2831853071795864f * (float)l / (float)L_SEQ;
  const float fstep = (15.0f - 1e-4f) / 15.0f;

  if (o == 0) zs[lq][0] = t;
  if (o >= 1 && o < 1 + BANDS) {
    int j = o - 1;
    float fj = 1e-4f + fstep * (float)j;
    zs[lq][1 + j] = cosf(wang * fj);
  }
  if (o >= 1 + BANDS && o < 1 + 2 * BANDS) {
    int j = o - 1 - BANDS;
    float fj = 1e-4f + fstep * (float)j;
    zs[lq][1 + BANDS + j] = -sinf(wang * fj);
  }
  __syncthreads();

  float fo = fr[o];
  float a = b0[o];
  for (int e = 0; e < EMB_D; ++e) a += zs[lq][e] * w0[o * EMB_D + e];
  hs[lq][o] = sinf(fo * a);
  __syncthreads();

  a = b1[o];
  for (int e = 0; e < ORD; ++e) a += hs[lq][e] * w1[o * ORD + e];
  gs[lq][o] = sinf(fo * a);
  __syncthreads();

  a = b2[o];
  for (int e = 0; e < ORD; ++e) a += gs[lq][e] * w2[o * ORD + e];
  float h3 = sinf(fo * a);
  __syncthreads();
  hs[lq][o] = h3;
  __syncthreads();

  #pragma unroll
  for (int pass = 0; pass < 2; ++pass) {
    int hd = pass * 64 + o;
    float acc = 0.0f;
    for (int e = 0; e < ORD; ++e) acc += hs[lq][e] * wf[hd * ORD + e];
    float val = acc * expf(-t * fabsf(md[hd]));
    if (l == 0) val += Dv[hd];   // absorb D term into lag-0 tap
    filt[(size_t)hd * FSTRIDE + 256 + l] = val;
  }
}

// ---------------------------------------------------------------------------
// Kernel 2: depthwise causal 3-tap conv + layout transform.
// in : [L,B,NH,HD] f32  (c_orig = np*128 + hn)
// out: A[b][hd_fft][l][n1] f32, where c_orig = hd_fft*8 + n1 (the fftconv split)
// Block handles (b, np, 64-l tile) for all 128 hn; loops q/k/v.
// ---------------------------------------------------------------------------
#define TLC 64
__global__ void shortconv_kernel(const float* __restrict__ q_in,
                                 const float* __restrict__ k_in,
                                 const float* __restrict__ v_in,
                                 const float* __restrict__ scw,
                                 const float* __restrict__ scb,
                                 float* __restrict__ Aq, float* __restrict__ Ak,
                                 float* __restrict__ Av) {
  int bid = blockIdx.x;
  int lt = bid & 31;
  int np = (bid >> 5) & 7;
  int b = bid >> 8;
  int l0 = lt * TLC;
  int tid = threadIdx.x;

  __shared__ float xs[TLC + 2][HDD + 4];      // +4 pad: breaks 512B-stride bank aliasing
  __shared__ float wcs[HDD][4];               // w0,w1,w2,bias per hn

  const float* ins[3] = {q_in, k_in, v_in};
  float* outs[3] = {Aq, Ak, Av};

  for (int tsr = 0; tsr < 3; ++tsr) {
    const float* x = ins[tsr];
    if (tid < HDD) {
      int c = np * HDD + tid;
      wcs[tid][0] = scw[(tsr * C_SZ + c) * 3 + 0];
      wcs[tid][1] = scw[(tsr * C_SZ + c) * 3 + 1];
      wcs[tid][2] = scw[(tsr * C_SZ + c) * 3 + 2];
      wcs[tid][3] = scb[tsr * C_SZ + c];
    }
    for (int idx = tid; idx < (TLC + 2) * HDD; idx += 256) {
      int row = idx >> 7, hn = idx & 127;
      int l = l0 - 2 + row;                  // row 0 <-> l0-2
      float val = 0.0f;
      if (l >= 0) val = x[(((size_t)l * B_SZ + b) * NHH + np) * HDD + hn];
      xs[row][hn] = val;
    }
    __syncthreads();

    int n1 = tid & 7;
    int lp = tid >> 3;                        // 0..31
    float* outp = outs[tsr];
    for (int hdi = 0; hdi < 16; ++hdi) {
      int hn = hdi * 8 + n1;
      float cw0 = wcs[hn][0], cw1 = wcs[hn][1], cw2 = wcs[hn][2], cb = wcs[hn][3];
      int hd = np * 16 + hdi;
      #pragma unroll
      for (int half = 0; half < 2; ++half) {
        int ll = half * 32 + lp;
        // y[l] = b + w0*x[l-2] + w1*x[l-1] + w2*x[l]
        float y = cb + cw0 * xs[ll][hn] + cw1 * xs[ll + 1][hn]
                     + cw2 * xs[ll + 2][hn];
        outp[(((size_t)b * HDD + hd) * L_SEQ + (l0 + ll)) * NHH + n1] = y;
      }
    }
    __syncthreads();
  }
}

// ---------------------------------------------------------------------------
// Kernel 3: main causal outer-product conv.
// out[b,.,l,.] = sum_{m<=l} filt[hd][l-m] * (sum_n1 Aq[l,n1]*Av[m,n1]) * Ak[m,n2]
// Grid = 2048 = (b, hd, l-tile of 256). Block = 4 waves; wave w owns 64 rows
// l = t0 + w*64 + lane. m-loop chunked by 256 with LDS staging:
//   av_s/ak_s: chunk rows (uniform broadcast reads in the hot loop)
//   f_s: filter window (lane-consecutive reads, 2-way bank alias = free)
// Causality via the 256-zero pad in front of each filter row.
// ---------------------------------------------------------------------------
#define MC 256
__global__ void __launch_bounds__(256, 6)
hyena_main(const float* __restrict__ Aq, const float* __restrict__ Ak,
           const float* __restrict__ Av, const float* __restrict__ filt,
           float* __restrict__ out) {
  int bid = blockIdx.x;                 // 2048 = B * HD * 8
  int tile = bid & 7;
  int hd = (bid >> 3) & 127;
  int b = bid >> 10;
  int t0 = tile * 256;
  int tid = threadIdx.x;
  int wave = tid >> 6;
  int lane = tid & 63;
  int l = t0 + wave * 64 + lane;        // this thread's output row

  __shared__ float av_s[MC][8];
  __shared__ float ak_s[MC][8];
  __shared__ float f_s[512];

  const float* fp = filt + (size_t)hd * FSTRIDE + 256;   // lag-0 position
  size_t base = ((size_t)b * HDD + hd) * L_SEQ * NHH;

  float qv[8], acc[8];
  {
    const float4* qp = (const float4*)(Aq + base + (size_t)l * 8);
    float4 q0 = qp[0], q1 = qp[1];
    qv[0] = q0.x; qv[1] = q0.y; qv[2] = q0.z; qv[3] = q0.w;
    qv[4] = q1.x; qv[5] = q1.y; qv[6] = q1.z; qv[7] = q1.w;
  }
  #pragma unroll
  for (int j = 0; j < 8; ++j) acc[j] = 0.0f;

  const float4* avg = (const float4*)(Av + base);  // float4 granularity: row m -> idx 2m
  const float4* akg = (const float4*)(Ak + base);

  int nch = tile + 1;                   // chunks cover m in [0, t0+256)
  int fbase = wave * 64 + lane + 256;   // f_s index = fbase - j  (in [1,511])
  for (int c = 0; c < nch; ++c) {
    int mc = c * MC;
    __syncthreads();                    // previous chunk fully consumed
    {
      float4* dst = (float4*)&av_s[0][0];
      dst[tid]       = avg[mc * 2 + tid];
      dst[tid + 256] = avg[mc * 2 + tid + 256];
      dst = (float4*)&ak_s[0][0];
      dst[tid]       = akg[mc * 2 + tid];
      dst[tid + 256] = akg[mc * 2 + tid + 256];
      // filter window: lags [t0-mc-256, t0-mc+255]; start is 256-aligned -> f4 ok
      if (tid < 128) ((float4*)f_s)[tid] = ((const float4*)(fp + (t0 - mc - 256)))[tid];
    }
    __syncthreads();

    #pragma unroll 2
    for (int j = 0; j < MC; ++j) {
      const float4* ap = (const float4*)av_s[j];
      float4 a0 = ap[0], a1 = ap[1];    // uniform -> LDS broadcast
      const float4* kp = (const float4*)ak_s[j];
      float4 k0 = kp[0], k1 = kp[1];
      float S = qv[0]*a0.x + qv[1]*a0.y + qv[2]*a0.z + qv[3]*a0.w
              + qv[4]*a1.x + qv[5]*a1.y + qv[6]*a1.z + qv[7]*a1.w;
      float tt = f_s[fbase - j] * S;    // 0.0 from pad when m > l
      acc[0] += tt*k0.x; acc[1] += tt*k0.y; acc[2] += tt*k0.z; acc[3] += tt*k0.w;
      acc[4] += tt*k1.x; acc[5] += tt*k1.y; acc[6] += tt*k1.z; acc[7] += tt*k1.w;
    }
  }

  // out[b, np, l, hn]: np = hd>>4, hn = (hd&15)*8 + n2 -> 8 contiguous f32
  int np = hd >> 4;
  int hnb = (hd & 15) * 8;
  size_t oidx = (((size_t)b * NHH + np) * L_SEQ + l) * HDD + hnb;
  float4* op = (float4*)(out + oidx);
  op[0] = make_float4(acc[0], acc[1], acc[2], acc[3]);
  op[1] = make_float4(acc[4], acc[5], acc[6], acc[7]);
}

// ---------------------------------------------------------------------------
extern "C" void kernel_launch(void* const* d_in, const int* in_sizes, int n_in,
                              void* d_out, int out_size, void* d_ws, size_t ws_size,
                              hipStream_t stream) {
  const float* q_in = (const float*)d_in[0];
  const float* k_in = (const float*)d_in[1];
  const float* v_in = (const float*)d_in[2];
  const float* scw  = (const float*)d_in[3];
  const float* scb  = (const float*)d_in[4];
  const float* Dv   = (const float*)d_in[5];
  const float* w0   = (const float*)d_in[6];
  const float* b0   = (const float*)d_in[7];
  const float* w1   = (const float*)d_in[8];
  const float* b1   = (const float*)d_in[9];
  const float* w2   = (const float*)d_in[10];
  const float* b2   = (const float*)d_in[11];
  const float* fr   = (const float*)d_in[12];
  const float* wf   = (const float*)d_in[13];
  const float* md   = (const float*)d_in[14];

  float* ws   = (float*)d_ws;
  float* filt = ws;                                        // 128*2304 f32
  float* Aq   = ws + (size_t)HDD * FSTRIDE;                // each 2*128*2048*8 f32
  float* Ak   = Aq + (size_t)B_SZ * HDD * L_SEQ * NHH;
  float* Av   = Ak + (size_t)B_SZ * HDD * L_SEQ * NHH;

  filter_kernel<<<512, 256, 0, stream>>>(w0, b0, w1, b1, w2, b2, fr, wf, md, Dv, filt);
  shortconv_kernel<<<512, 256, 0, stream>>>(q_in, k_in, v_in, scw, scb, Aq, Ak, Av);
  hyena_main<<<2048, 256, 0, stream>>>(Aq, Ak, Av, filt, (float*)d_out);
}

// Round 5
// 427.302 us; speedup vs baseline: 2.2846x; 1.5061x over previous
//
#include <hip/hip_runtime.h>
#include <stdint.h>

#define L_SEQ 2048
#define B_SZ 2
#define NHH 8
#define HDD 128
#define C_SZ 1024
#define EMB_D 33
#define ORD 64
#define BANDS 16
#define FSTRIDE (L_SEQ + 256)   // 256 leading zeros per filter row for causal masking

// ---------------------------------------------------------------------------
// Kernel 1: hyena filter MLP -> filt[hd][FSTRIDE] f32 (row = 256 zeros | 2048 taps)
// Block = 256 threads = 4 l-values x 64 "order" lanes. grid = 512.
// filt[hd][lag 0] += D[hd]  (absorbs the kv*D term).
// ---------------------------------------------------------------------------
__global__ void filter_kernel(const float* __restrict__ w0, const float* __restrict__ b0,
                              const float* __restrict__ w1, const float* __restrict__ b1,
                              const float* __restrict__ w2, const float* __restrict__ b2,
                              const float* __restrict__ fr, const float* __restrict__ wf,
                              const float* __restrict__ md, const float* __restrict__ Dv,
                              float* __restrict__ filt) {
  int tid = threadIdx.x;
  int o = tid & 63;
  int lq = tid >> 6;                 // 0..3
  int l = blockIdx.x * 4 + lq;

  // zero the 256-elem pad before each of the 128 filter rows (first 128 blocks)
  if (blockIdx.x < 128) filt[(size_t)blockIdx.x * FSTRIDE + tid] = 0.0f;

  __shared__ float zs[4][EMB_D];
  __shared__ float hs[4][ORD];
  __shared__ float gs[4][ORD];

  float t = (float)l / (float)(L_SEQ - 1);
  float wang = 6.2831853071795864f * (float)l / (float)L_SEQ;
  const float fstep = (15.0f - 1e-4f) / 15.0f;

  if (o == 0) zs[lq][0] = t;
  if (o >= 1 && o < 1 + BANDS) {
    int j = o - 1;
    float fj = 1e-4f + fstep * (float)j;
    zs[lq][1 + j] = cosf(wang * fj);
  }
  if (o >= 1 + BANDS && o < 1 + 2 * BANDS) {
    int j = o - 1 - BANDS;
    float fj = 1e-4f + fstep * (float)j;
    zs[lq][1 + BANDS + j] = -sinf(wang * fj);
  }
  __syncthreads();

  float fo = fr[o];
  float a = b0[o];
  for (int e = 0; e < EMB_D; ++e) a += zs[lq][e] * w0[o * EMB_D + e];
  hs[lq][o] = sinf(fo * a);
  __syncthreads();

  a = b1[o];
  for (int e = 0; e < ORD; ++e) a += hs[lq][e] * w1[o * ORD + e];
  gs[lq][o] = sinf(fo * a);
  __syncthreads();

  a = b2[o];
  for (int e = 0; e < ORD; ++e) a += gs[lq][e] * w2[o * ORD + e];
  float h3 = sinf(fo * a);
  __syncthreads();
  hs[lq][o] = h3;
  __syncthreads();

  #pragma unroll
  for (int pass = 0; pass < 2; ++pass) {
    int hd = pass * 64 + o;
    float acc = 0.0f;
    for (int e = 0; e < ORD; ++e) acc += hs[lq][e] * wf[hd * ORD + e];
    float val = acc * expf(-t * fabsf(md[hd]));
    if (l == 0) val += Dv[hd];   // absorb D term into lag-0 tap
    filt[(size_t)hd * FSTRIDE + 256 + l] = val;
  }
}

// ---------------------------------------------------------------------------
// Kernel 2: depthwise causal 3-tap conv + layout transform.
// in : [L,B,NH,HD] f32  (c_orig = np*128 + hn)
// out: A[b][hd_fft][l][n1] f32, where c_orig = hd_fft*8 + n1 (the fftconv split)
// Block handles (b, np, 64-l tile) for all 128 hn; loops q/k/v.
// ---------------------------------------------------------------------------
#define TLC 64
__global__ void shortconv_kernel(const float* __restrict__ q_in,
                                 const float* __restrict__ k_in,
                                 const float* __restrict__ v_in,
                                 const float* __restrict__ scw,
                                 const float* __restrict__ scb,
                                 float* __restrict__ Aq, float* __restrict__ Ak,
                                 float* __restrict__ Av) {
  int bid = blockIdx.x;
  int lt = bid & 31;
  int np = (bid >> 5) & 7;
  int b = bid >> 8;
  int l0 = lt * TLC;
  int tid = threadIdx.x;

  __shared__ float xs[TLC + 2][HDD + 4];      // +4 pad: breaks 512B-stride bank aliasing
  __shared__ float wcs[HDD][4];               // w0,w1,w2,bias per hn

  const float* ins[3] = {q_in, k_in, v_in};
  float* outs[3] = {Aq, Ak, Av};

  for (int tsr = 0; tsr < 3; ++tsr) {
    const float* x = ins[tsr];
    if (tid < HDD) {
      int c = np * HDD + tid;
      wcs[tid][0] = scw[(tsr * C_SZ + c) * 3 + 0];
      wcs[tid][1] = scw[(tsr * C_SZ + c) * 3 + 1];
      wcs[tid][2] = scw[(tsr * C_SZ + c) * 3 + 2];
      wcs[tid][3] = scb[tsr * C_SZ + c];
    }
    for (int idx = tid; idx < (TLC + 2) * HDD; idx += 256) {
      int row = idx >> 7, hn = idx & 127;
      int l = l0 - 2 + row;                  // row 0 <-> l0-2
      float val = 0.0f;
      if (l >= 0) val = x[(((size_t)l * B_SZ + b) * NHH + np) * HDD + hn];
      xs[row][hn] = val;
    }
    __syncthreads();

    int n1 = tid & 7;
    int lp = tid >> 3;                        // 0..31
    float* outp = outs[tsr];
    for (int hdi = 0; hdi < 16; ++hdi) {
      int hn = hdi * 8 + n1;
      float cw0 = wcs[hn][0], cw1 = wcs[hn][1], cw2 = wcs[hn][2], cb = wcs[hn][3];
      int hd = np * 16 + hdi;
      #pragma unroll
      for (int half = 0; half < 2; ++half) {
        int ll = half * 32 + lp;
        // y[l] = b + w0*x[l-2] + w1*x[l-1] + w2*x[l]
        float y = cb + cw0 * xs[ll][hn] + cw1 * xs[ll + 1][hn]
                     + cw2 * xs[ll + 2][hn];
        outp[(((size_t)b * HDD + hd) * L_SEQ + (l0 + ll)) * NHH + n1] = y;
      }
    }
    __syncthreads();
  }
}

// ---------------------------------------------------------------------------
// Kernel 3: main causal outer-product conv, triangle-balanced.
// out[b,.,l,.] = sum_{m<=l} filt[hd][l-m] * (sum_n1 Aq[l,n1]*Av[m,n1]) * Ak[m,n2]
// Grid = 1024 = (b, hd, p in 0..3). Block processes tile p THEN tile 7-p:
// (p+1) + (8-p) = 9 chunks for every block -> zero tail imbalance.
// Within a tile: 4 waves x 64 rows; m-loop chunked by 256 with LDS staging.
// Diagonal chunk: per-wave early exit (jend = 64*(wave+1)).
// Causality via the 256-zero pad in front of each filter row.
// ---------------------------------------------------------------------------
#define MC 256
__global__ void __launch_bounds__(256, 4)
hyena_main(const float* __restrict__ Aq, const float* __restrict__ Ak,
           const float* __restrict__ Av, const float* __restrict__ filt,
           float* __restrict__ out) {
  int bid = blockIdx.x;                 // 1024 = B * HD * 4
  int p = bid & 3;
  int hd = (bid >> 2) & 127;
  int b = bid >> 9;
  int tid = threadIdx.x;
  int wave = tid >> 6;
  int lane = tid & 63;

  __shared__ float av_s[MC][8];
  __shared__ float ak_s[MC][8];
  __shared__ float f_s[512];

  const float* fp = filt + (size_t)hd * FSTRIDE + 256;   // lag-0 position
  size_t base = ((size_t)b * HDD + hd) * L_SEQ * NHH;
  const float4* avg = (const float4*)(Av + base);  // row m -> float4 idx 2m
  const float4* akg = (const float4*)(Ak + base);

  int fbase = wave * 64 + lane + 256;   // f_s index = fbase - j  (always >= 1)
  int np = hd >> 4;
  int hnb = (hd & 15) * 8;

  #pragma unroll
  for (int half = 0; half < 2; ++half) {
    int tile = half == 0 ? p : 7 - p;
    int t0 = tile * 256;
    int l = t0 + wave * 64 + lane;      // this thread's output row

    float qv[8], acc[8];
    {
      const float4* qp = (const float4*)(Aq + base + (size_t)l * 8);
      float4 q0 = qp[0], q1 = qp[1];
      qv[0] = q0.x; qv[1] = q0.y; qv[2] = q0.z; qv[3] = q0.w;
      qv[4] = q1.x; qv[5] = q1.y; qv[6] = q1.z; qv[7] = q1.w;
    }
    #pragma unroll
    for (int j = 0; j < 8; ++j) acc[j] = 0.0f;

    for (int c = 0; c <= tile; ++c) {
      int mc = c * MC;
      __syncthreads();                  // previous chunk fully consumed
      {
        float4* dst = (float4*)&av_s[0][0];
        dst[tid]       = avg[mc * 2 + tid];
        dst[tid + 256] = avg[mc * 2 + tid + 256];
        dst = (float4*)&ak_s[0][0];
        dst[tid]       = akg[mc * 2 + tid];
        dst[tid + 256] = akg[mc * 2 + tid + 256];
        // filter window: lags [t0-mc-256, t0-mc+255]; 256-aligned -> float4 ok
        if (tid < 128) ((float4*)f_s)[tid] = ((const float4*)(fp + (t0 - mc - 256)))[tid];
      }
      __syncthreads();

      // diagonal chunk: rows of wave w only need j <= 64*w+63
      int jend = (c == tile) ? (wave * 64 + 64) : MC;
      #pragma unroll 4
      for (int j = 0; j < jend; ++j) {
        const float4* ap = (const float4*)av_s[j];
        float4 a0 = ap[0], a1 = ap[1];  // uniform -> LDS broadcast
        const float4* kp = (const float4*)ak_s[j];
        float4 k0 = kp[0], k1 = kp[1];
        float S = qv[0]*a0.x + qv[1]*a0.y + qv[2]*a0.z + qv[3]*a0.w
                + qv[4]*a1.x + qv[5]*a1.y + qv[6]*a1.z + qv[7]*a1.w;
        float tt = f_s[fbase - j] * S;  // 0.0 from pad when m > l
        acc[0] += tt*k0.x; acc[1] += tt*k0.y; acc[2] += tt*k0.z; acc[3] += tt*k0.w;
        acc[4] += tt*k1.x; acc[5] += tt*k1.y; acc[6] += tt*k1.z; acc[7] += tt*k1.w;
      }
    }

    // out[b, np, l, hn]: 8 contiguous f32 per row
    size_t oidx = (((size_t)b * NHH + np) * L_SEQ + l) * HDD + hnb;
    float4* op = (float4*)(out + oidx);
    op[0] = make_float4(acc[0], acc[1], acc[2], acc[3]);
    op[1] = make_float4(acc[4], acc[5], acc[6], acc[7]);

    __syncthreads();                    // LDS reused by next tile
  }
}

// ---------------------------------------------------------------------------
extern "C" void kernel_launch(void* const* d_in, const int* in_sizes, int n_in,
                              void* d_out, int out_size, void* d_ws, size_t ws_size,
                              hipStream_t stream) {
  const float* q_in = (const float*)d_in[0];
  const float* k_in = (const float*)d_in[1];
  const float* v_in = (const float*)d_in[2];
  const float* scw  = (const float*)d_in[3];
  const float* scb  = (const float*)d_in[4];
  const float* Dv   = (const float*)d_in[5];
  const float* w0   = (const float*)d_in[6];
  const float* b0   = (const float*)d_in[7];
  const float* w1   = (const float*)d_in[8];
  const float* b1   = (const float*)d_in[9];
  const float* w2   = (const float*)d_in[10];
  const float* b2   = (const float*)d_in[11];
  const float* fr   = (const float*)d_in[12];
  const float* wf   = (const float*)d_in[13];
  const float* md   = (const float*)d_in[14];

  float* ws   = (float*)d_ws;
  float* filt = ws;                                        // 128*2304 f32
  float* Aq   = ws + (size_t)HDD * FSTRIDE;                // each 2*128*2048*8 f32
  float* Ak   = Aq + (size_t)B_SZ * HDD * L_SEQ * NHH;
  float* Av   = Ak + (size_t)B_SZ * HDD * L_SEQ * NHH;

  filter_kernel<<<512, 256, 0, stream>>>(w0, b0, w1, b1, w2, b2, fr, wf, md, Dv, filt);
  shortconv_kernel<<<512, 256, 0, stream>>>(q_in, k_in, v_in, scw, scb, Aq, Ak, Av);
  hyena_main<<<1024, 256, 0, stream>>>(Aq, Ak, Av, filt, (float*)d_out);
}

// Round 6
// 234.864 us; speedup vs baseline: 4.1565x; 1.8194x over previous
//
#include <hip/hip_runtime.h>
#include <stdint.h>

#define L_SEQ 2048
#define B_SZ 2
#define NHH 8
#define HDD 128
#define C_SZ 1024
#define EMB_D 33
#define ORD 64
#define BANDS 16
#define FSTRIDE (L_SEQ + 256)   // 256 leading zeros per filter row for causal masking
#define FRS_STRIDE 2192         // 2176 used + 16 pad (stride ≡ 8 mod 32 dwords)

typedef _Float16 f16;
typedef f16 f16x8 __attribute__((ext_vector_type(8)));
typedef float f32x4 __attribute__((ext_vector_type(4)));

// ---------------------------------------------------------------------------
// Kernel 1: hyena filter MLP -> filt[hd][FSTRIDE] f32 (row = 256 zeros | 2048 taps)
// filt[hd][lag 0] += D[hd]  (absorbs the kv*D term).
// ---------------------------------------------------------------------------
__global__ void filter_kernel(const float* __restrict__ w0, const float* __restrict__ b0,
                              const float* __restrict__ w1, const float* __restrict__ b1,
                              const float* __restrict__ w2, const float* __restrict__ b2,
                              const float* __restrict__ fr, const float* __restrict__ wf,
                              const float* __restrict__ md, const float* __restrict__ Dv,
                              float* __restrict__ filt) {
  int tid = threadIdx.x;
  int o = tid & 63;
  int lq = tid >> 6;                 // 0..3
  int l = blockIdx.x * 4 + lq;

  if (blockIdx.x < 128) filt[(size_t)blockIdx.x * FSTRIDE + tid] = 0.0f;

  __shared__ float zs[4][EMB_D];
  __shared__ float hs[4][ORD];
  __shared__ float gs[4][ORD];

  float t = (float)l / (float)(L_SEQ - 1);
  float wang = 6.2831853071795864f * (float)l / (float)L_SEQ;
  const float fstep = (15.0f - 1e-4f) / 15.0f;

  if (o == 0) zs[lq][0] = t;
  if (o >= 1 && o < 1 + BANDS) {
    int j = o - 1;
    float fj = 1e-4f + fstep * (float)j;
    zs[lq][1 + j] = cosf(wang * fj);
  }
  if (o >= 1 + BANDS && o < 1 + 2 * BANDS) {
    int j = o - 1 - BANDS;
    float fj = 1e-4f + fstep * (float)j;
    zs[lq][1 + BANDS + j] = -sinf(wang * fj);
  }
  __syncthreads();

  float fo = fr[o];
  float a = b0[o];
  for (int e = 0; e < EMB_D; ++e) a += zs[lq][e] * w0[o * EMB_D + e];
  hs[lq][o] = sinf(fo * a);
  __syncthreads();

  a = b1[o];
  for (int e = 0; e < ORD; ++e) a += hs[lq][e] * w1[o * ORD + e];
  gs[lq][o] = sinf(fo * a);
  __syncthreads();

  a = b2[o];
  for (int e = 0; e < ORD; ++e) a += gs[lq][e] * w2[o * ORD + e];
  float h3 = sinf(fo * a);
  __syncthreads();
  hs[lq][o] = h3;
  __syncthreads();

  #pragma unroll
  for (int pass = 0; pass < 2; ++pass) {
    int hd = pass * 64 + o;
    float acc = 0.0f;
    for (int e = 0; e < ORD; ++e) acc += hs[lq][e] * wf[hd * ORD + e];
    float val = acc * expf(-t * fabsf(md[hd]));
    if (l == 0) val += Dv[hd];   // absorb D term into lag-0 tap
    filt[(size_t)hd * FSTRIDE + 256 + l] = val;
  }
}

// ---------------------------------------------------------------------------
// Kernel 2: depthwise causal 3-tap conv + layout transform (unchanged, passing).
// out: A[b][hd][l][n1] f32  (c_orig = hd*8 + n1)
// ---------------------------------------------------------------------------
#define TLC 64
__global__ void shortconv_kernel(const float* __restrict__ q_in,
                                 const float* __restrict__ k_in,
                                 const float* __restrict__ v_in,
                                 const float* __restrict__ scw,
                                 const float* __restrict__ scb,
                                 float* __restrict__ Aq, float* __restrict__ Ak,
                                 float* __restrict__ Av) {
  int bid = blockIdx.x;
  int lt = bid & 31;
  int np = (bid >> 5) & 7;
  int b = bid >> 8;
  int l0 = lt * TLC;
  int tid = threadIdx.x;

  __shared__ float xs[TLC + 2][HDD + 4];
  __shared__ float wcs[HDD][4];

  const float* ins[3] = {q_in, k_in, v_in};
  float* outs[3] = {Aq, Ak, Av};

  for (int tsr = 0; tsr < 3; ++tsr) {
    const float* x = ins[tsr];
    if (tid < HDD) {
      int c = np * HDD + tid;
      wcs[tid][0] = scw[(tsr * C_SZ + c) * 3 + 0];
      wcs[tid][1] = scw[(tsr * C_SZ + c) * 3 + 1];
      wcs[tid][2] = scw[(tsr * C_SZ + c) * 3 + 2];
      wcs[tid][3] = scb[tsr * C_SZ + c];
    }
    for (int idx = tid; idx < (TLC + 2) * HDD; idx += 256) {
      int row = idx >> 7, hn = idx & 127;
      int l = l0 - 2 + row;
      float val = 0.0f;
      if (l >= 0) val = x[(((size_t)l * B_SZ + b) * NHH + np) * HDD + hn];
      xs[row][hn] = val;
    }
    __syncthreads();

    int n1 = tid & 7;
    int lp = tid >> 3;
    float* outp = outs[tsr];
    for (int hdi = 0; hdi < 16; ++hdi) {
      int hn = hdi * 8 + n1;
      float cw0 = wcs[hn][0], cw1 = wcs[hn][1], cw2 = wcs[hn][2], cb = wcs[hn][3];
      int hd = np * 16 + hdi;
      #pragma unroll
      for (int half = 0; half < 2; ++half) {
        int ll = half * 32 + lp;
        float y = cb + cw0 * xs[ll][hn] + cw1 * xs[ll + 1][hn]
                     + cw2 * xs[ll + 2][hn];
        outp[(((size_t)b * HDD + hd) * L_SEQ + (l0 + ll)) * NHH + n1] = y;
      }
    }
    __syncthreads();
  }
}

// ---------------------------------------------------------------------------
// Kernel 3 (MFMA): per (b,hd):
//   G[l,n] = sum_{m<=l} W[l-m] * U[m,n],  U[m,n1*8+n2] = Av[m,n1]*Ak[m,n2]
//   out[l,n2] = sum_n1 Aq[l,n1] * G[l,n1*8+n2]
// Toeplitz A-operand from FRS (8 shift-copies of reversed W so every
// A-fragment is one aligned ds_read_b128); U built on the fly per m-chunk.
// 8 waves; wave w owns l-tile w (pass A) then 15-w (pass B); 128 VGPR acc.
// Causality: W[x<0] = 0 via filt's 256-zero pad.
// mfma_f32_16x16x32_f16 layouts: A row=lane&15, k=(lane>>4)*8+e;
// B col=lane&15, k=(lane>>4)*8+e; C/D col=lane&15, row=(lane>>4)*4+reg.
// ---------------------------------------------------------------------------
__global__ void __launch_bounds__(512, 2)
hyena_main(const float* __restrict__ Aq, const float* __restrict__ Ak,
           const float* __restrict__ Av, const float* __restrict__ filt,
           float* __restrict__ out) {
  int bid = blockIdx.x;            // 256 = B * HD
  int hd = bid & 127;
  int b  = bid >> 7;
  int tid = threadIdx.x;
  int w = tid >> 6;                // wave 0..7
  int lane = tid & 63;
  int r = lane & 15;               // A row / B col within 16
  int p = lane >> 4;               // k part 0..3
  int a = (15 - r) & 7;            // shift-copy class, = (7 - r) mod 8

  __shared__ f16 FRS[8][FRS_STRIDE];     // FRS[a][z] = W[2047 - z - a]
  __shared__ f16 Ut[2][64][144];         // Ut[buf][n][m_local], pad->144
  __shared__ float Qs[8][128][8];        // per-wave Q tile

  const float* frow = filt + (size_t)hd * FSTRIDE + 256;   // lag-0
  size_t base = ((size_t)b * HDD + hd) * (size_t)L_SEQ * NHH;
  const float* aqb = Aq + base;
  const float* avb = Av + base;
  const float* akb = Ak + base;
  int np = hd >> 4, hnb = (hd & 15) * 8;

  // ---- stage FRS (once per block); frow[-256..2047] is valid memory
  for (int aa = 0; aa < 8; ++aa)
    for (int z = tid; z < FRS_STRIDE; z += 512)
      FRS[aa][z] = (f16)frow[2047 - z - aa];

  f32x4 acc[8][4];

  // lambdas ---------------------------------------------------------------
  auto zero_acc = [&]() {
    #pragma unroll
    for (int mt = 0; mt < 8; ++mt)
      #pragma unroll
      for (int nt = 0; nt < 4; ++nt)
        acc[mt][nt] = f32x4{0.f, 0.f, 0.f, 0.f};
  };

  auto stage_q = [&](int l0) {           // wave-local
    const float4* src = (const float4*)(aqb + (size_t)l0 * 8);
    float4* dst = (float4*)&Qs[w][0][0];
    for (int ii = lane; ii < 256; ii += 64) dst[ii] = src[ii];
  };

  auto stage_ut = [&](int c, int bi) {   // all 512 threads
    int m = tid >> 2, q = tid & 3;
    const float* avp = avb + (size_t)(c * 128 + m) * 8;
    const float* akp = akb + (size_t)(c * 128 + m) * 8;
    float4 av0 = *(const float4*)avp;
    float4 av1 = *(const float4*)(avp + 4);
    float2 akq = *(const float2*)(akp + 2 * q);
    float avr[8] = {av0.x, av0.y, av0.z, av0.w, av1.x, av1.y, av1.z, av1.w};
    #pragma unroll
    for (int n1 = 0; n1 < 8; ++n1) {
      Ut[bi][n1 * 8 + 2 * q][m]     = (f16)(avr[n1] * akq.x);
      Ut[bi][n1 * 8 + 2 * q + 1][m] = (f16)(avr[n1] * akq.y);
    }
  };

  auto unit = [&](int lt, int c, int bi) {
    int dy = 2047 - (lt - c) * 128;
    int zlane = dy - r - a + p * 8;      // z = zlane - mt*16 + s*32 (8-aligned)
    #pragma unroll
    for (int s = 0; s < 4; ++s) {
      f16x8 bf[4];
      #pragma unroll
      for (int nt = 0; nt < 4; ++nt)
        bf[nt] = *(const f16x8*)&Ut[bi][nt * 16 + r][s * 32 + p * 8];
      #pragma unroll
      for (int mt = 0; mt < 8; ++mt) {
        f16x8 af = *(const f16x8*)&FRS[a][zlane - mt * 16 + s * 32];
        #pragma unroll
        for (int nt = 0; nt < 4; ++nt)
          acc[mt][nt] = __builtin_amdgcn_mfma_f32_16x16x32_f16(
              af, bf[nt], acc[mt][nt], 0, 0, 0);
      }
    }
  };

  auto epilogue = [&](int lt) {
    int l0 = lt * 128;
    int hi = (lane >> 3) & 1;            // (lane&15) >> 3
    int n2 = lane & 7;
    #pragma unroll
    for (int mt = 0; mt < 8; ++mt) {
      #pragma unroll
      for (int reg = 0; reg < 4; ++reg) {
        int i = mt * 16 + p * 4 + reg;
        float pr = 0.f;
        #pragma unroll
        for (int nt = 0; nt < 4; ++nt)
          pr += Qs[w][i][nt * 2 + hi] * acc[mt][nt][reg];
        pr += __shfl_xor(pr, 8, 64);
        if (r < 8) {
          size_t oidx = (((size_t)b * NHH + np) * L_SEQ + (l0 + i)) * HDD + hnb + n2;
          out[oidx] = pr;
        }
      }
    }
  };
  // ------------------------------------------------------------------------

  // pass A: tiles 0..7 (wave w -> tile w)
  stage_q(w * 128);
  zero_acc();
  for (int c = 0; c < 8; ++c) {
    stage_ut(c, c & 1);
    __syncthreads();
    if (w >= c) unit(w, c, c & 1);
    if (w == c) epilogue(w);
  }
  __syncthreads();

  // pass B: tiles 8..15 (wave w -> tile 15-w)
  int ltb = 15 - w;
  stage_q(ltb * 128);
  zero_acc();
  for (int c = 0; c < 16; ++c) {
    stage_ut(c, c & 1);
    __syncthreads();
    if (ltb >= c) unit(ltb, c, c & 1);
    if (ltb == c) epilogue(ltb);
  }
}

// ---------------------------------------------------------------------------
extern "C" void kernel_launch(void* const* d_in, const int* in_sizes, int n_in,
                              void* d_out, int out_size, void* d_ws, size_t ws_size,
                              hipStream_t stream) {
  const float* q_in = (const float*)d_in[0];
  const float* k_in = (const float*)d_in[1];
  const float* v_in = (const float*)d_in[2];
  const float* scw  = (const float*)d_in[3];
  const float* scb  = (const float*)d_in[4];
  const float* Dv   = (const float*)d_in[5];
  const float* w0   = (const float*)d_in[6];
  const float* b0   = (const float*)d_in[7];
  const float* w1   = (const float*)d_in[8];
  const float* b1   = (const float*)d_in[9];
  const float* w2   = (const float*)d_in[10];
  const float* b2   = (const float*)d_in[11];
  const float* fr   = (const float*)d_in[12];
  const float* wf   = (const float*)d_in[13];
  const float* md   = (const float*)d_in[14];

  float* ws   = (float*)d_ws;
  float* filt = ws;                                        // 128*2304 f32
  float* Aq   = ws + (size_t)HDD * FSTRIDE;                // each 2*128*2048*8 f32
  float* Ak   = Aq + (size_t)B_SZ * HDD * L_SEQ * NHH;
  float* Av   = Ak + (size_t)B_SZ * HDD * L_SEQ * NHH;

  filter_kernel<<<512, 256, 0, stream>>>(w0, b0, w1, b1, w2, b2, fr, wf, md, Dv, filt);
  shortconv_kernel<<<512, 256, 0, stream>>>(q_in, k_in, v_in, scw, scb, Aq, Ak, Av);
  hyena_main<<<256, 512, 0, stream>>>(Aq, Ak, Av, filt, (float*)d_out);
}

// Round 7
// 190.512 us; speedup vs baseline: 5.1242x; 1.2328x over previous
//
#include <hip/hip_runtime.h>
#include <stdint.h>

#define L_SEQ 2048
#define B_SZ 2
#define NHH 8
#define HDD 128
#define C_SZ 1024
#define EMB_D 33
#define ORD 64
#define BANDS 16
#define FSTRIDE (L_SEQ + 256)   // 256 leading zeros per filter row for causal masking
#define FRS_STRIDE 2192         // 2176 used + 16 pad
#define AKST 136                // Avt/Akt inner stride (f16)
#define QTS 136                 // Qt inner stride (f32)

typedef _Float16 f16;
typedef f16 f16x8 __attribute__((ext_vector_type(8)));
typedef f16 f16x4 __attribute__((ext_vector_type(4)));
typedef float f32x4 __attribute__((ext_vector_type(4)));

// ---------------------------------------------------------------------------
// Kernel 1: hyena filter MLP -> filt[hd][FSTRIDE] f32 (row = 256 zeros | 2048 taps)
// filt[hd][lag 0] += D[hd]  (absorbs the kv*D term).
// ---------------------------------------------------------------------------
__global__ void filter_kernel(const float* __restrict__ w0, const float* __restrict__ b0,
                              const float* __restrict__ w1, const float* __restrict__ b1,
                              const float* __restrict__ w2, const float* __restrict__ b2,
                              const float* __restrict__ fr, const float* __restrict__ wf,
                              const float* __restrict__ md, const float* __restrict__ Dv,
                              float* __restrict__ filt) {
  int tid = threadIdx.x;
  int o = tid & 63;
  int lq = tid >> 6;                 // 0..3
  int l = blockIdx.x * 4 + lq;

  if (blockIdx.x < 128) filt[(size_t)blockIdx.x * FSTRIDE + tid] = 0.0f;

  __shared__ float zs[4][EMB_D];
  __shared__ float hs[4][ORD];
  __shared__ float gs[4][ORD];

  float t = (float)l / (float)(L_SEQ - 1);
  float wang = 6.2831853071795864f * (float)l / (float)L_SEQ;
  const float fstep = (15.0f - 1e-4f) / 15.0f;

  if (o == 0) zs[lq][0] = t;
  if (o >= 1 && o < 1 + BANDS) {
    int j = o - 1;
    float fj = 1e-4f + fstep * (float)j;
    zs[lq][1 + j] = cosf(wang * fj);
  }
  if (o >= 1 + BANDS && o < 1 + 2 * BANDS) {
    int j = o - 1 - BANDS;
    float fj = 1e-4f + fstep * (float)j;
    zs[lq][1 + BANDS + j] = -sinf(wang * fj);
  }
  __syncthreads();

  float fo = fr[o];
  float a = b0[o];
  for (int e = 0; e < EMB_D; ++e) a += zs[lq][e] * w0[o * EMB_D + e];
  hs[lq][o] = sinf(fo * a);
  __syncthreads();

  a = b1[o];
  for (int e = 0; e < ORD; ++e) a += hs[lq][e] * w1[o * ORD + e];
  gs[lq][o] = sinf(fo * a);
  __syncthreads();

  a = b2[o];
  for (int e = 0; e < ORD; ++e) a += gs[lq][e] * w2[o * ORD + e];
  float h3 = sinf(fo * a);
  __syncthreads();
  hs[lq][o] = h3;
  __syncthreads();

  #pragma unroll
  for (int pass = 0; pass < 2; ++pass) {
    int hd = pass * 64 + o;
    float acc = 0.0f;
    for (int e = 0; e < ORD; ++e) acc += hs[lq][e] * wf[hd * ORD + e];
    float val = acc * expf(-t * fabsf(md[hd]));
    if (l == 0) val += Dv[hd];   // absorb D term into lag-0 tap
    filt[(size_t)hd * FSTRIDE + 256 + l] = val;
  }
}

// ---------------------------------------------------------------------------
// Kernel 2: depthwise causal 3-tap conv + layout transform (unchanged, passing).
// out: A[b][hd][l][n1] f32  (c_orig = hd*8 + n1)
// ---------------------------------------------------------------------------
#define TLC 64
__global__ void shortconv_kernel(const float* __restrict__ q_in,
                                 const float* __restrict__ k_in,
                                 const float* __restrict__ v_in,
                                 const float* __restrict__ scw,
                                 const float* __restrict__ scb,
                                 float* __restrict__ Aq, float* __restrict__ Ak,
                                 float* __restrict__ Av) {
  int bid = blockIdx.x;
  int lt = bid & 31;
  int np = (bid >> 5) & 7;
  int b = bid >> 8;
  int l0 = lt * TLC;
  int tid = threadIdx.x;

  __shared__ float xs[TLC + 2][HDD + 4];
  __shared__ float wcs[HDD][4];

  const float* ins[3] = {q_in, k_in, v_in};
  float* outs[3] = {Aq, Ak, Av};

  for (int tsr = 0; tsr < 3; ++tsr) {
    const float* x = ins[tsr];
    if (tid < HDD) {
      int c = np * HDD + tid;
      wcs[tid][0] = scw[(tsr * C_SZ + c) * 3 + 0];
      wcs[tid][1] = scw[(tsr * C_SZ + c) * 3 + 1];
      wcs[tid][2] = scw[(tsr * C_SZ + c) * 3 + 2];
      wcs[tid][3] = scb[tsr * C_SZ + c];
    }
    for (int idx = tid; idx < (TLC + 2) * HDD; idx += 256) {
      int row = idx >> 7, hn = idx & 127;
      int l = l0 - 2 + row;
      float val = 0.0f;
      if (l >= 0) val = x[(((size_t)l * B_SZ + b) * NHH + np) * HDD + hn];
      xs[row][hn] = val;
    }
    __syncthreads();

    int n1 = tid & 7;
    int lp = tid >> 3;
    float* outp = outs[tsr];
    for (int hdi = 0; hdi < 16; ++hdi) {
      int hn = hdi * 8 + n1;
      float cw0 = wcs[hn][0], cw1 = wcs[hn][1], cw2 = wcs[hn][2], cb = wcs[hn][3];
      int hd = np * 16 + hdi;
      #pragma unroll
      for (int half = 0; half < 2; ++half) {
        int ll = half * 32 + lp;
        float y = cb + cw0 * xs[ll][hn] + cw1 * xs[ll + 1][hn]
                     + cw2 * xs[ll + 2][hn];
        outp[(((size_t)b * HDD + hd) * L_SEQ + (l0 + ll)) * NHH + n1] = y;
      }
    }
    __syncthreads();
  }
}

// ---------------------------------------------------------------------------
// Kernel 3 (MFMA v2): per (b,hd):
//   G[l,n] = sum_{m<=l} W[l-m] * U[m,n],  U[m,n1*8+n2] = Av[m,n1]*Ak[m,n2]
//   out[l,n2] = sum_n1 Aq[l,n1] * G[l,n1*8+n2]
// Changes vs v1: (a) Toeplitz A-fragment register reuse: only 14 distinct
// frags per unit (f[2s-mt+7]); (b) B-fragments built in-register from
// transposed Avt/Akt[8][136] (broadcast reads, conflict-free, v_pk_mul_f16);
// (c) Qt transposed -> float4 conflict-free epilogue reads; (d) 512 blocks
// (2/CU), 4 waves, tile-pairs balanced: g0={0..3}+{15..12}, g1={4..7}+{11..8}
// -> every block 20 chunk-iters / 68 units; every wave 17 units;
// (e) stage loads software-pipelined under unit(c).
// mfma_f32_16x16x32_f16: A row=lane&15, k=(lane>>4)*8+e; B col=lane&15,
// k=(lane>>4)*8+e; C/D col=lane&15, row=(lane>>4)*4+reg.  (verified R6)
// ---------------------------------------------------------------------------
__global__ void __launch_bounds__(256, 2)
hyena_main(const float* __restrict__ Aq, const float* __restrict__ Ak,
           const float* __restrict__ Av, const float* __restrict__ filt,
           float* __restrict__ out) {
  int bid = blockIdx.x;            // 512 = B * HD * 2
  int g  = bid & 1;
  int hd = (bid >> 1) & 127;
  int b  = bid >> 8;
  int tid = threadIdx.x;
  int w = tid >> 6;                // wave 0..3
  int lane = tid & 63;
  int r = lane & 15;               // A row / B col within 16
  int p = lane >> 4;               // k part 0..3
  int a = (15 - r) & 7;            // FRS shift-copy class

  __shared__ f16 FRS[8][FRS_STRIDE];   // FRS[a][z] = W[2047 - z - a]
  __shared__ f16 Avt[2][8][AKST];      // Avt[buf][n1][m_local]
  __shared__ f16 Akt[2][8][AKST];      // Akt[buf][n2][m_local]
  __shared__ float Qt[4][8][QTS];      // Qt[wave][n1][l_local]

  const float* frow = filt + (size_t)hd * FSTRIDE + 256;   // lag-0
  size_t base = ((size_t)b * HDD + hd) * (size_t)L_SEQ * NHH;
  const float* aqb = Aq + base;
  const float* avb = Av + base;
  const float* akb = Ak + base;
  int np = hd >> 4, hnb = (hd & 15) * 8;

  // ---- stage FRS once; frow[-256..2047] is valid (zero pad in front)
  for (int idx = tid; idx < 8 * FRS_STRIDE; idx += 256) {
    int aa = idx / FRS_STRIDE;
    int z  = idx - aa * FRS_STRIDE;
    FRS[aa][z] = (f16)frow[2047 - z - aa];
  }

  f32x4 acc[8][4];
  int sn = tid & 7, sm = tid >> 3;     // staging coords: n=sn, m0=4*sm
  float rA[4], rK[4];

  auto stage_load = [&](int c) {
    const float* sa = avb + (size_t)(c * 128 + 4 * sm) * 8 + sn;
    const float* sk = akb + (size_t)(c * 128 + 4 * sm) * 8 + sn;
    rA[0] = sa[0]; rA[1] = sa[8]; rA[2] = sa[16]; rA[3] = sa[24];
    rK[0] = sk[0]; rK[1] = sk[8]; rK[2] = sk[16]; rK[3] = sk[24];
  };
  auto stage_write = [&](int bi) {
    f16x4 va = {(f16)rA[0], (f16)rA[1], (f16)rA[2], (f16)rA[3]};
    f16x4 vk = {(f16)rK[0], (f16)rK[1], (f16)rK[2], (f16)rK[3]};
    *(f16x4*)&Avt[bi][sn][4 * sm] = va;
    *(f16x4*)&Akt[bi][sn][4 * sm] = vk;
  };

  auto stage_qt = [&](int l0) {        // wave-local transpose stage of Q tile
    const float4* src = (const float4*)(aqb + (size_t)l0 * 8);
    #pragma unroll
    for (int rr = 0; rr < 2; ++rr) {
      int i = rr * 64 + lane;
      float4 q0 = src[i * 2], q1 = src[i * 2 + 1];
      Qt[w][0][i] = q0.x; Qt[w][1][i] = q0.y; Qt[w][2][i] = q0.z; Qt[w][3][i] = q0.w;
      Qt[w][4][i] = q1.x; Qt[w][5][i] = q1.y; Qt[w][6][i] = q1.z; Qt[w][7][i] = q1.w;
    }
  };

  auto unit = [&](int lt, int c, int bi) {
    int dy = 2047 - (lt - c) * 128;
    int zbase = dy - r - a + p * 8 - 112;     // f[dd] <-> d = dd-7
    f16x8 f[14];
    #pragma unroll
    for (int dd = 0; dd < 14; ++dd)
      f[dd] = *(const f16x8*)&FRS[a][zbase + 16 * dd];
    #pragma unroll
    for (int s = 0; s < 4; ++s) {
      f16x8 kf = *(const f16x8*)&Akt[bi][r & 7][s * 32 + p * 8];
      #pragma unroll
      for (int nt = 0; nt < 4; ++nt) {
        f16x8 vf = *(const f16x8*)&Avt[bi][nt * 2 + (r >> 3)][s * 32 + p * 8];
        f16x8 bf = vf * kf;                    // v_pk_mul_f16
        #pragma unroll
        for (int mt = 0; mt < 8; ++mt)
          acc[mt][nt] = __builtin_amdgcn_mfma_f32_16x16x32_f16(
              f[7 + 2 * s - mt], bf, acc[mt][nt], 0, 0, 0);
      }
    }
  };

  auto epilogue = [&](int lt) {
    int l0 = lt * 128;
    int hi = r >> 3;
    int n2 = r & 7;
    #pragma unroll
    for (int mt = 0; mt < 8; ++mt) {
      float4 qv[4];
      #pragma unroll
      for (int nt = 0; nt < 4; ++nt)
        qv[nt] = *(const float4*)&Qt[w][nt * 2 + hi][mt * 16 + p * 4];
      #pragma unroll
      for (int reg = 0; reg < 4; ++reg) {
        float pr = qv[0][reg] * acc[mt][0][reg] + qv[1][reg] * acc[mt][1][reg]
                 + qv[2][reg] * acc[mt][2][reg] + qv[3][reg] * acc[mt][3][reg];
        pr += __shfl_xor(pr, 8, 64);
        if (r < 8) {
          int i = mt * 16 + p * 4 + reg;
          out[(((size_t)b * NHH + np) * L_SEQ + (l0 + i)) * HDD + hnb + n2] = pr;
        }
      }
    }
  };

  auto run_pass = [&](int mytile, int NC) {
    stage_qt(mytile * 128);
    #pragma unroll
    for (int mt = 0; mt < 8; ++mt)
      #pragma unroll
      for (int nt = 0; nt < 4; ++nt)
        acc[mt][nt] = f32x4{0.f, 0.f, 0.f, 0.f};
    stage_load(0);
    for (int c = 0; c < NC; ++c) {
      stage_write(c & 1);
      __syncthreads();                 // buf c&1 ready; units(c-1) all done
      if (c + 1 < NC) stage_load(c + 1);   // global latency hides under unit(c)
      if (mytile >= c) unit(mytile, c, c & 1);
      if (mytile == c) epilogue(mytile);
    }
    __syncthreads();
  };

  // pass A: tiles g*4+w (NC = g*4+4); pass B: tiles 15-g*4-w (NC = 16-g*4)
  run_pass(g * 4 + w, g * 4 + 4);
  run_pass(15 - g * 4 - w, 16 - g * 4);
}

// ---------------------------------------------------------------------------
extern "C" void kernel_launch(void* const* d_in, const int* in_sizes, int n_in,
                              void* d_out, int out_size, void* d_ws, size_t ws_size,
                              hipStream_t stream) {
  const float* q_in = (const float*)d_in[0];
  const float* k_in = (const float*)d_in[1];
  const float* v_in = (const float*)d_in[2];
  const float* scw  = (const float*)d_in[3];
  const float* scb  = (const float*)d_in[4];
  const float* Dv   = (const float*)d_in[5];
  const float* w0   = (const float*)d_in[6];
  const float* b0   = (const float*)d_in[7];
  const float* w1   = (const float*)d_in[8];
  const float* b1   = (const float*)d_in[9];
  const float* w2   = (const float*)d_in[10];
  const float* b2   = (const float*)d_in[11];
  const float* fr   = (const float*)d_in[12];
  const float* wf   = (const float*)d_in[13];
  const float* md   = (const float*)d_in[14];

  float* ws   = (float*)d_ws;
  float* filt = ws;                                        // 128*2304 f32
  float* Aq   = ws + (size_t)HDD * FSTRIDE;                // each 2*128*2048*8 f32
  float* Ak   = Aq + (size_t)B_SZ * HDD * L_SEQ * NHH;
  float* Av   = Ak + (size_t)B_SZ * HDD * L_SEQ * NHH;

  filter_kernel<<<512, 256, 0, stream>>>(w0, b0, w1, b1, w2, b2, fr, wf, md, Dv, filt);
  shortconv_kernel<<<512, 256, 0, stream>>>(q_in, k_in, v_in, scw, scb, Aq, Ak, Av);
  hyena_main<<<512, 256, 0, stream>>>(Aq, Ak, Av, filt, (float*)d_out);
}